// Round 1
// baseline (454.874 us; speedup 1.0000x reference)
//
#include <hip/hip_runtime.h>
#include <math.h>

#define N_SAMP 32768
#define NBLK   1024   // main-kernel grid

// ---------- helpers ----------

__device__ __forceinline__ float dot4(const float4& a, const float4& b) {
    return a.x*b.x + a.y*b.y + a.z*b.z + a.w*b.w;
}

template<int CTRL>
__device__ __forceinline__ float dpp_add(float x) {
    int y = __builtin_amdgcn_update_dpp(0, __float_as_int(x), CTRL, 0xF, 0xF, true);
    return x + __int_as_float(y);
}

// After this, lane 31 of each 32-lane half holds the 32-lane sum.
// (row_shr:1/2/4/8 builds row-16 prefix sums; row_bcast:15 folds row0->row1.)
__device__ __forceinline__ float sum32_last(float x) {
    x = dpp_add<0x111>(x);   // row_shr:1
    x = dpp_add<0x112>(x);   // row_shr:2
    x = dpp_add<0x114>(x);   // row_shr:4
    x = dpp_add<0x118>(x);   // row_shr:8
    x = dpp_add<0x142>(x);   // row_bcast:15
    return x;
}

__device__ __forceinline__ float red32_all(float v) {
    v += __shfl_xor(v, 1);
    v += __shfl_xor(v, 2);
    v += __shfl_xor(v, 4);
    v += __shfl_xor(v, 8);
    v += __shfl_xor(v, 16);
    return v;
}

__device__ __forceinline__ void gfadd(float* p, float v) {
    __hip_atomic_fetch_add(p, v, __ATOMIC_RELAXED, __HIP_MEMORY_SCOPE_AGENT);
}
__device__ __forceinline__ void lfadd(float* p, float v) {
    __hip_atomic_fetch_add(p, v, __ATOMIC_RELAXED, __HIP_MEMORY_SCOPE_WORKGROUP);
}

// ---------- main kernel ----------
// block = 256 threads = 4 waves = 8 half-wave groups; each group owns one sample
// per iteration (exactly 4 iterations at NBLK=1024).

template<bool ATOMIC>
__global__ __launch_bounds__(256, 4) void nssd_main(const float* __restrict__ gf,
                                                    const float* __restrict__ cc,
                                                    float* __restrict__ ws)
{
    __shared__ float lds_ccn[2048];
    __shared__ float lds_acc[2048];
    __shared__ float lds_red[16];

    const int tid  = threadIdx.x;
    const int lane = tid & 31;
    const int grp  = tid >> 5;

    #pragma unroll
    for (int i = 0; i < 8; ++i) lds_acc[tid + i*256] = 0.0f;

    // normalize cluster_center stripe `grp` into LDS (8 groups == 8 stripes)
    {
        const float4* cc4 = (const float4*)cc;
        float4 a = cc4[grp*64 + lane];
        float4 b = cc4[grp*64 + 32 + lane];
        float ss  = red32_all(dot4(a,a) + dot4(b,b));
        float inv = 1.0f / (sqrtf(ss) + 1e-12f);
        float4* l4 = (float4*)lds_ccn;
        l4[grp*64 + lane]      = make_float4(a.x*inv, a.y*inv, a.z*inv, a.w*inv);
        l4[grp*64 + 32 + lane] = make_float4(b.x*inv, b.y*inv, b.z*inv, b.w*inv);
    }
    __syncthreads();

    float l1acc = 0.0f, l2acc = 0.0f;

    for (int n = blockIdx.x*8 + grp; n < N_SAMP; n += NBLK*8) {
        const float4* gp = (const float4*)(gf + (size_t)n * 2048);
        float4 ga[8], gb[8];
        #pragma unroll
        for (int s = 0; s < 8; ++s) {
            ga[s] = gp[s*64 + lane];        // dims s*256 + lane*4 .. +3
            gb[s] = gp[s*64 + 32 + lane];   // dims s*256 + 128 + lane*4 .. +3
        }

        float inv[8];
        #pragma unroll
        for (int s = 0; s < 8; ++s) {
            float ss = sum32_last(dot4(ga[s],ga[s]) + dot4(gb[s],gb[s]));
            ss = __shfl(ss, 31, 32);        // broadcast group sum to all 32 lanes
            inv[s] = 1.0f / (sqrtf(ss) + 1e-12f);
        }

        // accumulate once-normalized g into block accumulator
        // permuted layout: slot = s*256 + idx*32 + lane  (idx = j*4+k) -> conflict-free
        #pragma unroll
        for (int s = 0; s < 8; ++s) {
            float* base = &lds_acc[s*256 + lane];
            lfadd(base + 0*32, ga[s].x*inv[s]);
            lfadd(base + 1*32, ga[s].y*inv[s]);
            lfadd(base + 2*32, ga[s].z*inv[s]);
            lfadd(base + 3*32, ga[s].w*inv[s]);
            lfadd(base + 4*32, gb[s].x*inv[s]);
            lfadd(base + 5*32, gb[s].y*inv[s]);
            lfadd(base + 6*32, gb[s].z*inv[s]);
            lfadd(base + 7*32, gb[s].w*inv[s]);
        }

        // loss1: sum |C - I| ; C symmetric -> diag once + off-diag twice
        #pragma unroll
        for (int s = 0; s < 8; ++s) {
            #pragma unroll
            for (int t = s; t < 8; ++t) {
                float p = dot4(ga[s],ga[t]) + dot4(gb[s],gb[t]);
                float c = sum32_last(p) * (inv[s]*inv[t]);   // valid on lane 31
                l1acc += (s==t) ? fabsf(c - 1.0f) : 2.0f*fabsf(c);
            }
        }

        // loss2: D = clip((1 - gn.ccn)/2, 1e-12); diag & min over t (with +1 on diag)
        float dmin[8], ddiag[8];
        #pragma unroll
        for (int s = 0; s < 8; ++s) dmin[s] = 1e30f;
        const float4* cn4 = (const float4*)lds_ccn;
        #pragma unroll
        for (int t = 0; t < 8; ++t) {
            float4 ca = cn4[t*64 + lane];
            float4 cb = cn4[t*64 + 32 + lane];
            #pragma unroll
            for (int s = 0; s < 8; ++s) {
                float p  = dot4(ga[s],ca) + dot4(gb[s],cb);
                float e  = sum32_last(p) * inv[s];           // valid on lane 31
                float dd = fmaxf(fmaf(-0.5f, e, 0.5f), 1e-12f);
                if (s == t) { ddiag[s] = dd; dd += 1.0f; }
                dmin[s] = fminf(dmin[s], dd);
            }
        }
        #pragma unroll
        for (int s = 0; s < 8; ++s) {
            float x = ddiag[s] - dmin[s];
            l2acc += __logf(1.0f + __expf(x));               // softplus
        }
    }

    __syncthreads();                       // lds_acc atomics complete
    if ((tid & 31) == 31) {                // lane 31 holds the valid group sums
        lds_red[grp]     = l1acc;
        lds_red[8 + grp] = l2acc;
    }
    __syncthreads();

    if (ATOMIC) {
        #pragma unroll
        for (int i = 0; i < 8; ++i) {
            int p = tid + i*256;
            gfadd(&ws[p], lds_acc[p]);
        }
        if (tid == 0) {
            float s1 = 0.f, s2 = 0.f;
            #pragma unroll
            for (int i = 0; i < 8; ++i) { s1 += lds_red[i]; s2 += lds_red[8+i]; }
            gfadd(&ws[2048], s1);
            gfadd(&ws[2049], s2);
        }
    } else {
        float* wb = ws + (size_t)blockIdx.x * 2048;
        #pragma unroll
        for (int i = 0; i < 8; ++i) {
            int p = tid + i*256;
            wb[p] = lds_acc[p];
        }
        if (tid == 0) {
            float s1 = 0.f, s2 = 0.f;
            #pragma unroll
            for (int i = 0; i < 8; ++i) { s1 += lds_red[i]; s2 += lds_red[8+i]; }
            ws[(size_t)NBLK*2048 + blockIdx.x]        = s1;
            ws[(size_t)NBLK*2048 + NBLK + blockIdx.x] = s2;
        }
    }
}

// ---------- finalize ----------
// blocks 0..7: new_cc slots (un-permute acc layout); block 8: loss reduction.

template<int NB>
__global__ __launch_bounds__(256) void nssd_finalize(const float* __restrict__ ws,
                                                     const float* __restrict__ cc,
                                                     float* __restrict__ out,
                                                     int loff)
{
    if (blockIdx.x < 8) {
        int p = blockIdx.x * 256 + threadIdx.x;   // permuted slot
        float s = 0.0f;
        #pragma unroll 4
        for (int k = 0; k < NB; ++k) s += ws[(size_t)k*2048 + p];
        int st = p >> 8, r = p & 255, idx = r >> 5, ln = r & 31;
        int d  = ((idx >> 2) * 128) + ln*4 + (idx & 3);
        int o  = st*256 + d;
        out[1 + o] = 0.9f*cc[o] + 0.1f*(s * (1.0f/32768.0f));
    } else {
        const float* lp = ws + loff;
        float s1 = 0.f, s2 = 0.f;
        for (int i = threadIdx.x; i < NB; i += 256) { s1 += lp[i]; s2 += lp[NB + i]; }
        #pragma unroll
        for (int m = 1; m <= 32; m <<= 1) { s1 += __shfl_xor(s1, m); s2 += __shfl_xor(s2, m); }
        __shared__ float r1[4], r2[4];
        int w = threadIdx.x >> 6;
        if ((threadIdx.x & 63) == 0) { r1[w] = s1; r2[w] = s2; }
        __syncthreads();
        if (threadIdx.x == 0) {
            float a = r1[0] + r1[1] + r1[2] + r1[3];
            float b = r2[0] + r2[1] + r2[2] + r2[3];
            out[0] = a * (1.0f/(32768.0f*64.0f)) + b * (1.0f/(32768.0f*8.0f));
        }
    }
}

// ---------- launch ----------

extern "C" void kernel_launch(void* const* d_in, const int* in_sizes, int n_in,
                              void* d_out, int out_size, void* d_ws, size_t ws_size,
                              hipStream_t stream)
{
    const float* gf = (const float*)d_in[0];
    const float* cc = (const float*)d_in[1];
    float* out = (float*)d_out;
    float* ws  = (float*)d_ws;

    const size_t need_store = (size_t)(NBLK*2048 + 2*NBLK) * sizeof(float);

    if (ws_size >= need_store) {
        hipLaunchKernelGGL((nssd_main<false>), dim3(NBLK), dim3(256), 0, stream, gf, cc, ws);
        hipLaunchKernelGGL((nssd_finalize<NBLK>), dim3(9), dim3(256), 0, stream,
                           ws, cc, out, NBLK*2048);
    } else {
        hipMemsetAsync(ws, 0, 2050*sizeof(float), stream);
        hipLaunchKernelGGL((nssd_main<true>), dim3(NBLK), dim3(256), 0, stream, gf, cc, ws);
        hipLaunchKernelGGL((nssd_finalize<1>), dim3(9), dim3(256), 0, stream,
                           ws, cc, out, 2048);
    }
}

// Round 2
// 171.609 us; speedup vs baseline: 2.6506x; 2.6506x over previous
//
#include <hip/hip_runtime.h>
#include <hip/hip_bf16.h>
#include <math.h>

#define N_SAMP 32768
#define NPAIR  (N_SAMP/2)
#define NBLK   1024

typedef short bf16x8 __attribute__((ext_vector_type(8)));
typedef float f32x4  __attribute__((ext_vector_type(4)));

__device__ __forceinline__ float dot4(const float4& a, const float4& b) {
    return a.x*b.x + a.y*b.y + a.z*b.z + a.w*b.w;
}

__device__ __forceinline__ ushort f2bfu(float x) {
    __hip_bfloat16 h = __float2bfloat16(x);
    ushort u; __builtin_memcpy(&u, &h, 2); return u;
}
__device__ __forceinline__ unsigned int pk2bf(float x, float y) {
    return (unsigned int)f2bfu(x) | ((unsigned int)f2bfu(y) << 16);
}

__device__ __forceinline__ void gfadd(float* p, float v) {
    __hip_atomic_fetch_add(p, v, __ATOMIC_RELAXED, __HIP_MEMORY_SCOPE_AGENT);
}

// ---------------- main kernel ----------------
// 256 threads = 4 waves. Each wave owns a PAIR of samples per iteration:
// a 16-row x 256-col tile (row = local_sample*8 + stripe).
// Gram = mfma(A,A) -> norms from diag; E = mfma(A, ccnB). No block barrier
// in the main loop (per-wave LDS regions only).

template<bool ATOMIC>
__global__ __launch_bounds__(256) void nssd_main(const float* __restrict__ gf,
                                                 const float* __restrict__ cc,
                                                 float* __restrict__ ws)
{
    __shared__ unsigned int lds_raw[8192];   // 32 KB: staging / ccn tmp / colsum tmp
    __shared__ float lds_inv[4][16];
    __shared__ float lds_red[8];

    const int tid  = threadIdx.x;
    const int lane = tid & 63;
    const int w    = tid >> 6;

    // ---- normalize cluster_center into f32 LDS (temporary use of lds_raw) ----
    {
        float* cptr = (float*)lds_raw;
        const int l32 = tid & 31, st = tid >> 5;
        const float4* cc4 = (const float4*)cc;
        float4 a = cc4[st*64 + l32];
        float4 b = cc4[st*64 + 32 + l32];
        float ss = dot4(a,a) + dot4(b,b);
        #pragma unroll
        for (int m = 1; m < 32; m <<= 1) ss += __shfl_xor(ss, m);
        float inv = 1.0f / (sqrtf(ss) + 1e-12f);
        *(float4*)(cptr + st*256 + l32*4)       = make_float4(a.x*inv, a.y*inv, a.z*inv, a.w*inv);
        *(float4*)(cptr + st*256 + 128 + l32*4) = make_float4(b.x*inv, b.y*inv, b.z*inv, b.w*inv);
    }
    __syncthreads();

    // ---- build B-fragments of ccn (cols 8..15 duplicate cols 0..7) ----
    bf16x8 ccnB[8];
    {
        const float* cptr = (const float*)lds_raw;
        #pragma unroll
        for (int kb = 0; kb < 8; ++kb) {
            int d0 = kb*32 + (lane >> 4)*8;
            float4 c0 = *(const float4*)(cptr + (lane & 7)*256 + d0);
            float4 c1 = *(const float4*)(cptr + (lane & 7)*256 + d0 + 4);
            uint4 u;
            u.x = pk2bf(c0.x, c0.y); u.y = pk2bf(c0.z, c0.w);
            u.z = pk2bf(c1.x, c1.y); u.w = pk2bf(c1.z, c1.w);
            __builtin_memcpy(&ccnB[kb], &u, 16);
        }
    }
    __syncthreads();   // ccn reads done before staging overwrites lds_raw

    char* sbase = (char*)lds_raw + w*8192;
    const int g = lane >> 4, c = lane & 15;
    const int rrow = c;                     // A-frag row for this lane

    f32x4 colacc[8];
    #pragma unroll
    for (int s = 0; s < 8; ++s) colacc[s] = (f32x4){0.f,0.f,0.f,0.f};
    float l1 = 0.f, l2 = 0.f;

    for (int p = blockIdx.x*4 + w; p < NPAIR; p += NBLK*4) {
        const float4* g4 = (const float4*)(gf + (size_t)p * 4096);

        // ---- load f32 coalesced, cvt to bf16, stage XOR-swizzled ----
        #pragma unroll
        for (int h = 0; h < 2; ++h) {
            float4 v[8];
            #pragma unroll
            for (int i = 0; i < 8; ++i) v[i] = g4[(h*8+i)*64 + lane];
            #pragma unroll
            for (int i = 0; i < 8; ++i) {
                int row = h*8 + i;
                uint2 u;
                u.x = pk2bf(v[i].x, v[i].y);
                u.y = pk2bf(v[i].z, v[i].w);
                *(uint2*)(sbase + row*512 + ((lane*8) ^ ((row & 7) << 4))) = u;
            }
        }

        // ---- MFMA: Gram (A,A) and E (A, ccnB), K = 256 in 8 steps ----
        f32x4 accg = (f32x4){0.f,0.f,0.f,0.f};
        f32x4 acce = (f32x4){0.f,0.f,0.f,0.f};
        #pragma unroll
        for (int kb = 0; kb < 8; ++kb) {
            int d0 = kb*32 + g*8;
            bf16x8 afrag = *(bf16x8*)(sbase + rrow*512 + ((d0*2) ^ ((rrow & 7) << 4)));
            accg = __builtin_amdgcn_mfma_f32_16x16x32_bf16(afrag, afrag,    accg, 0, 0, 0);
            acce = __builtin_amdgcn_mfma_f32_16x16x32_bf16(afrag, ccnB[kb], acce, 0, 0, 0);
        }

        // ---- inv factors from Gram diagonal; broadcast via per-wave LDS ----
        float xd = (lane&3)==0 ? accg[0] : (lane&3)==1 ? accg[1]
                 : (lane&3)==2 ? accg[2] : accg[3];
        float invv = 1.0f / (sqrtf(xd) + 1e-12f);
        if (g == (c >> 2)) lds_inv[w][c] = invv;     // diag lane for row r=c
        f32x4 invrow = *(f32x4*)&lds_inv[w][g*4];    // inv for my 4 rows
        float invcol = lds_inv[w][c];                // inv for my col

        // ---- losses ----
        #pragma unroll
        for (int reg = 0; reg < 4; ++reg) {
            int r = g*4 + reg;
            // loss1: |C - I| restricted to same-sample 8x8 blocks
            float C = accg[reg] * invrow[reg] * invcol;
            bool inblk = ((r >> 3) == (c >> 3));
            float tgt = (r == c) ? 1.0f : 0.0f;
            l1 += inblk ? fabsf(C - tgt) : 0.0f;

            // loss2: D = clip((1-e)/2, 1e-12); min over t (diag +1); softplus
            float e  = acce[reg] * invrow[reg];
            float Dv = fmaxf(fmaf(-0.5f, e, 0.5f), 1e-12f);
            bool ond = ((c & 7) == (r & 7));
            float dmin = Dv + (ond ? 1.0f : 0.0f);
            float ddia = ond ? Dv : 3e38f;
            #pragma unroll
            for (int m = 1; m < 16; m <<= 1) {
                dmin = fminf(dmin, __shfl_xor(dmin, m));
                ddia = fminf(ddia, __shfl_xor(ddia, m));
            }
            float sp = __logf(1.0f + __expf(ddia - dmin));
            l2 += (c == (r & 7)) ? sp : 0.0f;
        }

        // ---- colsum of normalized g (EMA) from staged bf16 ----
        f32x4 iv0 = *(f32x4*)&lds_inv[w][0];
        f32x4 iv1 = *(f32x4*)&lds_inv[w][4];
        f32x4 iv2 = *(f32x4*)&lds_inv[w][8];
        f32x4 iv3 = *(f32x4*)&lds_inv[w][12];
        float invs[16] = { iv0[0],iv0[1],iv0[2],iv0[3], iv1[0],iv1[1],iv1[2],iv1[3],
                           iv2[0],iv2[1],iv2[2],iv2[3], iv3[0],iv3[1],iv3[2],iv3[3] };
        #pragma unroll
        for (int i = 0; i < 16; ++i) {
            uint2 u = *(uint2*)(sbase + i*512 + ((lane*8) ^ ((i & 7) << 4)));
            float x0 = __uint_as_float(u.x << 16);
            float x1 = __uint_as_float(u.x & 0xffff0000u);
            float x2 = __uint_as_float(u.y << 16);
            float x3 = __uint_as_float(u.y & 0xffff0000u);
            int s = i & 7;
            float iw = invs[i];
            colacc[s][0] += x0*iw; colacc[s][1] += x1*iw;
            colacc[s][2] += x2*iw; colacc[s][3] += x3*iw;
        }
    }

    // ---------------- block epilogue ----------------
    __syncthreads();   // everyone done with per-wave staging

    #pragma unroll
    for (int m = 1; m < 64; m <<= 1) { l1 += __shfl_xor(l1, m); l2 += __shfl_xor(l2, m); }
    if (lane == 0) { lds_red[w] = l1; lds_red[4 + w] = l2; }

    float* cf = (float*)lds_raw + w*2048;
    #pragma unroll
    for (int s = 0; s < 8; ++s)
        *(f32x4*)(cf + s*256 + lane*4) = colacc[s];
    __syncthreads();

    const float* lf = (const float*)lds_raw;
    if (ATOMIC) {
        #pragma unroll
        for (int c8 = 0; c8 < 8; ++c8) {
            int idx = c8*256 + tid;
            float v = lf[idx] + lf[2048+idx] + lf[4096+idx] + lf[6144+idx];
            gfadd(&ws[idx], v);
        }
        if (tid == 0) {
            gfadd(&ws[2048], lds_red[0]+lds_red[1]+lds_red[2]+lds_red[3]);
            gfadd(&ws[2049], lds_red[4]+lds_red[5]+lds_red[6]+lds_red[7]);
        }
    } else {
        float* wb = ws + (size_t)blockIdx.x * 2048;
        #pragma unroll
        for (int c8 = 0; c8 < 8; ++c8) {
            int idx = c8*256 + tid;
            wb[idx] = lf[idx] + lf[2048+idx] + lf[4096+idx] + lf[6144+idx];
        }
        if (tid == 0) {
            ws[(size_t)NBLK*2048 + blockIdx.x]        = lds_red[0]+lds_red[1]+lds_red[2]+lds_red[3];
            ws[(size_t)NBLK*2048 + NBLK + blockIdx.x] = lds_red[4]+lds_red[5]+lds_red[6]+lds_red[7];
        }
    }
}

// ---------------- finalize ----------------
// blocks 0..7: new_cc (layout is already s*256+d); block 8: loss.

template<int NB>
__global__ __launch_bounds__(256) void nssd_finalize(const float* __restrict__ ws,
                                                     const float* __restrict__ cc,
                                                     float* __restrict__ out,
                                                     int loff)
{
    if (blockIdx.x < 8) {
        int p = blockIdx.x * 256 + threadIdx.x;
        float s = 0.0f;
        #pragma unroll 4
        for (int k = 0; k < NB; ++k) s += ws[(size_t)k*2048 + p];
        out[1 + p] = 0.9f*cc[p] + 0.1f*(s * (1.0f/32768.0f));
    } else {
        const float* lp = ws + loff;
        float s1 = 0.f, s2 = 0.f;
        for (int i = threadIdx.x; i < NB; i += 256) { s1 += lp[i]; s2 += lp[NB + i]; }
        #pragma unroll
        for (int m = 1; m <= 32; m <<= 1) { s1 += __shfl_xor(s1, m); s2 += __shfl_xor(s2, m); }
        __shared__ float r1[4], r2[4];
        int w = threadIdx.x >> 6;
        if ((threadIdx.x & 63) == 0) { r1[w] = s1; r2[w] = s2; }
        __syncthreads();
        if (threadIdx.x == 0) {
            float a = r1[0] + r1[1] + r1[2] + r1[3];
            float b = r2[0] + r2[1] + r2[2] + r2[3];
            out[0] = a * (1.0f/(32768.0f*64.0f)) + b * (1.0f/(32768.0f*8.0f));
        }
    }
}

// ---------------- launch ----------------

extern "C" void kernel_launch(void* const* d_in, const int* in_sizes, int n_in,
                              void* d_out, int out_size, void* d_ws, size_t ws_size,
                              hipStream_t stream)
{
    const float* gf = (const float*)d_in[0];
    const float* cc = (const float*)d_in[1];
    float* out = (float*)d_out;
    float* ws  = (float*)d_ws;

    const size_t need_store = (size_t)(NBLK*2048 + 2*NBLK) * sizeof(float);

    if (ws_size >= need_store) {
        hipLaunchKernelGGL((nssd_main<false>), dim3(NBLK), dim3(256), 0, stream, gf, cc, ws);
        hipLaunchKernelGGL((nssd_finalize<NBLK>), dim3(9), dim3(256), 0, stream,
                           ws, cc, out, NBLK*2048);
    } else {
        hipMemsetAsync(ws, 0, 2050*sizeof(float), stream);
        hipLaunchKernelGGL((nssd_main<true>), dim3(NBLK), dim3(256), 0, stream, gf, cc, ws);
        hipLaunchKernelGGL((nssd_finalize<1>), dim3(9), dim3(256), 0, stream,
                           ws, cc, out, 2048);
    }
}

// Round 3
// 116.912 us; speedup vs baseline: 3.8908x; 1.4679x over previous
//
#include <hip/hip_runtime.h>
#include <hip/hip_bf16.h>
#include <math.h>

#define N_SAMP 32768
#define NPAIR  (N_SAMP/2)
#define NBLK   1024

typedef short bf16x8 __attribute__((ext_vector_type(8)));
typedef float f32x4  __attribute__((ext_vector_type(4)));

__device__ __forceinline__ float dot4(const float4& a, const float4& b) {
    return a.x*b.x + a.y*b.y + a.z*b.z + a.w*b.w;
}

__device__ __forceinline__ ushort f2bfu(float x) {
    __hip_bfloat16 h = __float2bfloat16(x);
    ushort u; __builtin_memcpy(&u, &h, 2); return u;
}
__device__ __forceinline__ unsigned int pk2bf(float x, float y) {
    return (unsigned int)f2bfu(x) | ((unsigned int)f2bfu(y) << 16);
}

__device__ __forceinline__ void gfadd(float* p, float v) {
    __hip_atomic_fetch_add(p, v, __ATOMIC_RELAXED, __HIP_MEMORY_SCOPE_AGENT);
}

// ---------------- main kernel ----------------
// 256 threads = 4 waves; each wave owns one PAIR of samples per iteration
// (16x256 bf16 tile). Gram = mfma(A,A) -> norms from diag; E = mfma(A,ccn).
// colsum (EMA) accumulated straight from the register-held bf16 values.
// No block barrier in the main loop.

template<bool ATOMIC>
__global__ __launch_bounds__(256, 4) void nssd_main(const float* __restrict__ gf,
                                                    const float* __restrict__ cc,
                                                    float* __restrict__ ws)
{
    __shared__ unsigned int lds_stage[4][2048];  // 32 KB: per-wave bf16 staging (also f32 tmp / cf tmp)
    __shared__ unsigned int lds_ccn[1024];       // 4 KB: ccn bf16 [8][256], XOR-swizzled
    __shared__ float lds_inv[4][16];
    __shared__ float lds_red[8];

    const int tid  = threadIdx.x;
    const int lane = tid & 63;
    const int w    = tid >> 6;

    // ---- normalize cluster_center into f32 (temp in lds_stage) ----
    {
        float* cptr = (float*)lds_stage;
        const int l32 = tid & 31, st = tid >> 5;
        const float4* cc4 = (const float4*)cc;
        float4 a = cc4[st*64 + l32];
        float4 b = cc4[st*64 + 32 + l32];
        float ss = dot4(a,a) + dot4(b,b);
        #pragma unroll
        for (int m = 1; m < 32; m <<= 1) ss += __shfl_xor(ss, m);
        float inv = 1.0f / (sqrtf(ss) + 1e-12f);
        *(float4*)(cptr + st*256 + l32*4)       = make_float4(a.x*inv, a.y*inv, a.z*inv, a.w*inv);
        *(float4*)(cptr + st*256 + 128 + l32*4) = make_float4(b.x*inv, b.y*inv, b.z*inv, b.w*inv);
    }
    __syncthreads();
    // ---- ccn -> bf16 LDS, swizzled: byte = row*512 + ((col*2) ^ ((row&7)<<4)) ----
    {
        const float* cptr = (const float*)lds_stage;
        int row = tid >> 5, c0 = (tid & 31) * 8;
        uint4 uu;
        uu.x = pk2bf(cptr[row*256+c0+0], cptr[row*256+c0+1]);
        uu.y = pk2bf(cptr[row*256+c0+2], cptr[row*256+c0+3]);
        uu.z = pk2bf(cptr[row*256+c0+4], cptr[row*256+c0+5]);
        uu.w = pk2bf(cptr[row*256+c0+6], cptr[row*256+c0+7]);
        *(uint4*)((char*)lds_ccn + row*512 + ((c0*2) ^ (row << 4))) = uu;
    }
    __syncthreads();

    char* sbase = (char*)lds_stage + w*8192;
    char* cbase = (char*)lds_ccn;
    const int g = lane >> 4, c = lane & 15;

    f32x4 colacc[8];
    #pragma unroll
    for (int s = 0; s < 8; ++s) colacc[s] = (f32x4){0.f,0.f,0.f,0.f};
    float l1 = 0.f, l2 = 0.f;

    for (int p = blockIdx.x*4 + w; p < NPAIR; p += NBLK*4) {
        const float4* g4 = (const float4*)(gf + (size_t)p * 4096);

        // ---- load f32 coalesced, cvt to bf16 (kept in regs), stage swizzled ----
        uint2 u[16];
        #pragma unroll
        for (int h = 0; h < 4; ++h) {
            float4 v0 = g4[(h*4+0)*64 + lane];
            float4 v1 = g4[(h*4+1)*64 + lane];
            float4 v2 = g4[(h*4+2)*64 + lane];
            float4 v3 = g4[(h*4+3)*64 + lane];
            u[h*4+0] = make_uint2(pk2bf(v0.x,v0.y), pk2bf(v0.z,v0.w));
            u[h*4+1] = make_uint2(pk2bf(v1.x,v1.y), pk2bf(v1.z,v1.w));
            u[h*4+2] = make_uint2(pk2bf(v2.x,v2.y), pk2bf(v2.z,v2.w));
            u[h*4+3] = make_uint2(pk2bf(v3.x,v3.y), pk2bf(v3.z,v3.w));
        }
        #pragma unroll
        for (int r = 0; r < 16; ++r)
            *(uint2*)(sbase + r*512 + ((lane*8) ^ ((r & 7) << 4))) = u[r];

        // ---- MFMA: Gram (A,A) and E (A,ccn), K=256 in 8 steps ----
        f32x4 accg = (f32x4){0.f,0.f,0.f,0.f};
        f32x4 acce = (f32x4){0.f,0.f,0.f,0.f};
        #pragma unroll
        for (int kb = 0; kb < 8; ++kb) {
            int off = kb*64 + g*16;
            bf16x8 afrag = *(bf16x8*)(sbase + c*512     + (off ^ ((c & 7) << 4)));
            bf16x8 cfrag = *(bf16x8*)(cbase + (c&7)*512 + (off ^ ((c & 7) << 4)));
            accg = __builtin_amdgcn_mfma_f32_16x16x32_bf16(afrag, afrag, accg, 0, 0, 0);
            acce = __builtin_amdgcn_mfma_f32_16x16x32_bf16(afrag, cfrag, acce, 0, 0, 0);
        }

        // ---- inv factors from Gram diag; broadcast via per-wave LDS ----
        float xd = (lane&3)==0 ? accg[0] : (lane&3)==1 ? accg[1]
                 : (lane&3)==2 ? accg[2] : accg[3];
        float invv = 1.0f / (sqrtf(xd) + 1e-12f);
        if (g == (c >> 2)) lds_inv[w][c] = invv;     // diag lane for row r=c
        f32x4 invrow = *(f32x4*)&lds_inv[w][g*4];
        float invcol = lds_inv[w][c];

        // ---- losses ----
        #pragma unroll
        for (int reg = 0; reg < 4; ++reg) {
            int r = g*4 + reg;
            float C = accg[reg] * invrow[reg] * invcol;
            bool inblk = ((r >> 3) == (c >> 3));
            float tgt = (r == c) ? 1.0f : 0.0f;
            l1 += inblk ? fabsf(C - tgt) : 0.0f;

            float e  = acce[reg] * invrow[reg];
            float Dv = fmaxf(fmaf(-0.5f, e, 0.5f), 1e-12f);
            bool ond = ((c & 7) == (r & 7));
            float dmin = Dv + (ond ? 1.0f : 0.0f);
            float ddia = ond ? Dv : 3e38f;
            #pragma unroll
            for (int m = 1; m < 16; m <<= 1) {
                dmin = fminf(dmin, __shfl_xor(dmin, m));
                ddia = fminf(ddia, __shfl_xor(ddia, m));
            }
            float sp = __logf(1.0f + __expf(ddia - dmin));
            l2 += (c == (r & 7)) ? sp : 0.0f;
        }

        // ---- colsum of normalized g straight from register-held bf16 ----
        #pragma unroll
        for (int i = 0; i < 16; ++i) {
            float iw = lds_inv[w][i];
            float x0 = __uint_as_float(u[i].x << 16);
            float x1 = __uint_as_float(u[i].x & 0xffff0000u);
            float x2 = __uint_as_float(u[i].y << 16);
            float x3 = __uint_as_float(u[i].y & 0xffff0000u);
            int s = i & 7;
            colacc[s][0] += x0*iw; colacc[s][1] += x1*iw;
            colacc[s][2] += x2*iw; colacc[s][3] += x3*iw;
        }
    }

    // ---------------- block epilogue ----------------
    __syncthreads();

    #pragma unroll
    for (int m = 1; m < 64; m <<= 1) { l1 += __shfl_xor(l1, m); l2 += __shfl_xor(l2, m); }
    if (lane == 0) { lds_red[w] = l1; lds_red[4 + w] = l2; }

    float* cf = (float*)lds_stage + w*2048;
    #pragma unroll
    for (int s = 0; s < 8; ++s)
        *(f32x4*)(cf + s*256 + lane*4) = colacc[s];
    __syncthreads();

    const float* lf = (const float*)lds_stage;
    if (ATOMIC) {
        #pragma unroll
        for (int c8 = 0; c8 < 8; ++c8) {
            int idx = c8*256 + tid;
            gfadd(&ws[idx], lf[idx] + lf[2048+idx] + lf[4096+idx] + lf[6144+idx]);
        }
        if (tid == 0) {
            gfadd(&ws[2048], lds_red[0]+lds_red[1]+lds_red[2]+lds_red[3]);
            gfadd(&ws[2049], lds_red[4]+lds_red[5]+lds_red[6]+lds_red[7]);
        }
    } else {
        float* wb = ws + (size_t)blockIdx.x * 2048;
        #pragma unroll
        for (int c8 = 0; c8 < 8; ++c8) {
            int idx = c8*256 + tid;
            wb[idx] = lf[idx] + lf[2048+idx] + lf[4096+idx] + lf[6144+idx];
        }
        if (tid == 0) {
            ws[(size_t)NBLK*2048 + blockIdx.x]        = lds_red[0]+lds_red[1]+lds_red[2]+lds_red[3];
            ws[(size_t)NBLK*2048 + NBLK + blockIdx.x] = lds_red[4]+lds_red[5]+lds_red[6]+lds_red[7];
        }
    }
}

// ---------------- finalize ----------------
// blocks 0..31: new_cc, 64 cols x 4 parallel k-chunks each; block 32: loss.

template<int NB>
__global__ __launch_bounds__(256) void nssd_finalize(const float* __restrict__ ws,
                                                     const float* __restrict__ cc,
                                                     float* __restrict__ out,
                                                     int loff)
{
    __shared__ float red[256];
    const int t = threadIdx.x;
    if (blockIdx.x < 32) {
        const int col = blockIdx.x*64 + (t & 63);
        const int kc  = t >> 6;                 // 0..3
        const int chunk = (NB + 3) / 4;
        const int k0 = kc * chunk;
        const int k1 = (k0 + chunk < NB) ? (k0 + chunk) : NB;
        float s0 = 0.f, s1 = 0.f, s2 = 0.f, s3 = 0.f;
        int k = k0;
        for (; k + 4 <= k1; k += 4) {
            s0 += ws[(size_t)(k+0)*2048 + col];
            s1 += ws[(size_t)(k+1)*2048 + col];
            s2 += ws[(size_t)(k+2)*2048 + col];
            s3 += ws[(size_t)(k+3)*2048 + col];
        }
        for (; k < k1; ++k) s0 += ws[(size_t)k*2048 + col];
        red[t] = (s0 + s1) + (s2 + s3);
        __syncthreads();
        if (t < 64) {
            float v = red[t] + red[t+64] + red[t+128] + red[t+192];
            int o = blockIdx.x*64 + t;
            out[1 + o] = 0.9f*cc[o] + 0.1f*(v * (1.0f/32768.0f));
        }
    } else {
        const float* lp = ws + loff;
        float s1 = 0.f, s2 = 0.f;
        for (int i = t; i < NB; i += 256) { s1 += lp[i]; s2 += lp[NB + i]; }
        #pragma unroll
        for (int m = 1; m <= 32; m <<= 1) { s1 += __shfl_xor(s1, m); s2 += __shfl_xor(s2, m); }
        if ((t & 63) == 0) { red[t >> 6] = s1; red[4 + (t >> 6)] = s2; }
        __syncthreads();
        if (t == 0) {
            float a = red[0] + red[1] + red[2] + red[3];
            float b = red[4] + red[5] + red[6] + red[7];
            out[0] = a * (1.0f/(32768.0f*64.0f)) + b * (1.0f/(32768.0f*8.0f));
        }
    }
}

// ---------------- launch ----------------

extern "C" void kernel_launch(void* const* d_in, const int* in_sizes, int n_in,
                              void* d_out, int out_size, void* d_ws, size_t ws_size,
                              hipStream_t stream)
{
    const float* gf = (const float*)d_in[0];
    const float* cc = (const float*)d_in[1];
    float* out = (float*)d_out;
    float* ws  = (float*)d_ws;

    const size_t need_store = (size_t)(NBLK*2048 + 2*NBLK) * sizeof(float);

    if (ws_size >= need_store) {
        hipLaunchKernelGGL((nssd_main<false>), dim3(NBLK), dim3(256), 0, stream, gf, cc, ws);
        hipLaunchKernelGGL((nssd_finalize<NBLK>), dim3(33), dim3(256), 0, stream,
                           ws, cc, out, NBLK*2048);
    } else {
        hipMemsetAsync(ws, 0, 2050*sizeof(float), stream);
        hipLaunchKernelGGL((nssd_main<true>), dim3(NBLK), dim3(256), 0, stream, gf, cc, ws);
        hipLaunchKernelGGL((nssd_finalize<1>), dim3(33), dim3(256), 0, stream,
                           ws, cc, out, 2048);
    }
}